// Round 9
// baseline (605.631 us; speedup 1.0000x reference)
//
#include <hip/hip_runtime.h>
#include <hip/hip_bf16.h>

typedef __bf16 bf16;
typedef unsigned long long u64;
typedef __bf16 bf16x8 __attribute__((ext_vector_type(8)));
typedef __bf16 bf16x4 __attribute__((ext_vector_type(4)));
typedef float f32x4 __attribute__((ext_vector_type(4)));

#define NB 4
#define T 8192
#define C 128
#define NBLK 40
#define XS 136   // LDS row stride (bf16): 128 ch + 8 pad

#define MFMA(a, b, c) __builtin_amdgcn_mfma_f32_16x16x32_bf16(a, b, c, 0, 0, 0)

__device__ __forceinline__ float bf2f(bf16 x){ return (float)x; }
__device__ __forceinline__ bf16 f2bf(float x){ return (bf16)x; }

__device__ __forceinline__ float ld(const void* p, int i, int isbf){
    return isbf ? bf2f(((const bf16*)p)[i]) : ((const float*)p)[i];
}

// Coherent 8B load (relaxed agent atomic -> bypasses stale L1/L2;
// compiler manages the waitcnt before use).
__device__ __forceinline__ bf16x4 ld8(const bf16* p){
    u64 v = __hip_atomic_load((const u64*)p, __ATOMIC_RELAXED, __HIP_MEMORY_SCOPE_AGENT);
    return __builtin_bit_cast(bf16x4, v);
}
// Coherent stores via asm (inputs only -> safe), caller drains vmcnt.
__device__ __forceinline__ void st16c(bf16* p, f32x4 v){
    asm volatile("global_store_dwordx4 %0, %1, off sc0 sc1" :: "v"(p), "v"(v) : "memory");
}
__device__ __forceinline__ void st8c(bf16* p, bf16x4 v){
    u64 u = __builtin_bit_cast(u64, v);
    asm volatile("global_store_dwordx2 %0, %1, off sc0 sc1" :: "v"(p), "v"(u) : "memory");
}

// Detect input dtype from x's raw bits (bf16 -> low u16s have sane exponents).
__global__ __launch_bounds__(64) void k_detect(const unsigned short* __restrict__ u,
                                               int* __restrict__ flag){
    unsigned short v = u[threadIdx.x * 2];
    int e = (v >> 7) & 255;
    bool sane = (e >= 100 && e <= 140) || ((v & 0x7FFF) == 0);
    unsigned long long m = __ballot(sane);
    if (threadIdx.x == 0) *flag = (__popcll(m) >= 48) ? 1 : 0;
}

// Canonicalize inputs (8 elems per thread).
// weff [40][256][256] bf16: weff[blk][o][c]=cw[blk][o][c][0] (t-d), [o][128+c]=cw[..][1] (t)
__global__ __launch_bounds__(256) void k_prep(
    const void* __restrict__ conv_w, const void* __restrict__ post_w,
    const void* __restrict__ lin1_w, const void* __restrict__ lin2_w,
    const void* __restrict__ x,      const void* __restrict__ conv_b,
    const void* __restrict__ post_b, const void* __restrict__ pre_w,
    const void* __restrict__ pre_b,  const void* __restrict__ lin1_b,
    const void* __restrict__ lin2_b,
    bf16* __restrict__ weff, bf16* __restrict__ pwc,
    bf16* __restrict__ w1c,  bf16* __restrict__ w2c,
    float* __restrict__ xc,  float* __restrict__ cbf,
    float* __restrict__ pbf, float* __restrict__ misc,
    const int* __restrict__ flag){
    int f = *flag;
    int g = blockIdx.x * 256 + threadIdx.x;
    if (g < 327680){                 // weff: 40*256*256/8 granules
        int blk = g >> 13, r = g & 8191, o = r >> 5, j = r & 31;
        int k = (j >= 16) ? 1 : 0;
        int base = blk * 65536 + o * 256 + (j * 8 - k * 128) * 2 + k;
        bf16x8 v;
#pragma unroll
        for (int m = 0; m < 8; m++) v[m] = f2bf(ld(conv_w, base + m * 2, f));
        *(bf16x8*)(weff + (size_t)g * 8) = v;
    } else if (g < 409600){          // pwc
        int e = (g - 327680) * 8;
        bf16x8 v;
#pragma unroll
        for (int m = 0; m < 8; m++) v[m] = f2bf(ld(post_w, e + m, f));
        *(bf16x8*)(pwc + e) = v;
    } else if (g < 411648){          // w1c
        int e = (g - 409600) * 8;
        bf16x8 v;
#pragma unroll
        for (int m = 0; m < 8; m++) v[m] = f2bf(ld(lin1_w, e + m, f));
        *(bf16x8*)(w1c + e) = v;
    } else if (g < 413696){          // w2c
        int e = (g - 411648) * 8;
        bf16x8 v;
#pragma unroll
        for (int m = 0; m < 8; m++) v[m] = f2bf(ld(lin2_w, e + m, f));
        *(bf16x8*)(w2c + e) = v;
    } else if (g < 417792){          // xc (f32)
        int e = (g - 413696) * 8;
#pragma unroll
        for (int m = 0; m < 8; m++) xc[e + m] = ld(x, e + m, f);
    } else if (g < 419072){          // cbf
        int e = (g - 417792) * 8;
#pragma unroll
        for (int m = 0; m < 8; m++) cbf[e + m] = ld(conv_b, e + m, f);
    } else if (g < 419712){          // pbf
        int e = (g - 419072) * 8;
#pragma unroll
        for (int m = 0; m < 8; m++) pbf[e + m] = ld(post_b, e + m, f);
    } else if (g < 419808){          // misc
        int e = (g - 419712) * 8;
#pragma unroll
        for (int m = 0; m < 8; m++){
            int idx = e + m;
            if      (idx < 384) misc[idx] = ld(pre_w,  idx,       f);
            else if (idx < 512) misc[idx] = ld(pre_b,  idx - 384, f);
            else if (idx < 640) misc[idx] = ld(lin1_b, idx - 512, f);
            else                misc[idx] = ld(lin2_b, idx - 640, f);
        }
    }
}

__device__ __forceinline__ void wait_ge(unsigned* p, unsigned v){
    int guard = 0;
    while (__hip_atomic_load(p, __ATOMIC_RELAXED, __HIP_MEMORY_SCOPE_AGENT) < v){
        __builtin_amdgcn_s_sleep(1);
        if (++guard > (1 << 22)) break;   // failsafe against protocol bugs
    }
    asm volatile("" ::: "memory");
}

// Store tail rows [128-nrows, 128) of Xo to dst (global, coherent), then drain.
// One row = 128 bf16 = 256 B = SIXTEEN 16B granules. (Used once, for pre-net.)
__device__ __forceinline__ void tail_store(const bf16* Xo, bf16* dst, int nrows, int tid){
    int ngr = nrows * 16;                      // 16B granules
    for (int g = tid; g < ngr; g += 512){
        int rr = 128 - nrows + (g >> 4), co = (g & 15) * 8;
        f32x4 v = *(const f32x4*)(Xo + rr * XS + co);
        st16c(dst + (size_t)rr * C + co, v);
    }
    asm volatile("s_waitcnt vmcnt(0)" ::: "memory");
}

// Persistent kernel, 256 WGs x 512 threads, 1 WG/CU (proven geometry).
// Round-5 merged structure, now THREE barriers/layer (was 5):
//   A: tap-t MFMA from Xo (no deps)  ||  poll prog (all threads)
//   B: stage Xh rows [t0-d, t0+128-d)            S1  (tid0 publishes cons)
//   C: tap-d MFMA from Xh
//   D: GLU -> S into Xs  (THIRD buffer: no WAR vs C's Xh reads -> old S2 gone)
//                                                 S2  (Xs visible)
//   E: post MFMA from Xs + residual -> Xo write; anti-overwrite poll;
//      tail cols stored DIRECTLY FROM REGISTERS (8B coherent) + own vmcnt drain
//      (no LDS re-read pass -> old S4 gone; merged with S5)
//                                                 S3  (Xo visible + stores drained)
//      tid0 publishes prog
// Handshake semantics byte-identical to the 456us round-5 kernel.
// prog[w] = stages published (pre=1, layer i => i+2); cons[w] = staging reads done.
__global__ __launch_bounds__(512, 2) void k_main(
    const float* __restrict__ xc,  const float* __restrict__ misc,
    const bf16* __restrict__ weff, const float* __restrict__ cbf,
    const bf16* __restrict__ pwc,  const float* __restrict__ pbf,
    const bf16* __restrict__ w1c,  const bf16* __restrict__ w2c,
    bf16* __restrict__ hA, bf16* __restrict__ hB,
    unsigned* __restrict__ prog, unsigned* __restrict__ cons,
    void* __restrict__ outv, const int* __restrict__ flag)
{
    __shared__ __align__(16) bf16 Xo[128 * XS];  // own h^{(i)} tile (34,816 B)
    __shared__ __align__(16) bf16 Xh[128 * XS];  // staged tap tile (34,816 B)
    __shared__ __align__(16) bf16 Xs[128 * XS];  // skip S / Z / U  (34,816 B)

    int tid  = threadIdx.x;
    int wg   = blockIdx.x;             // 256
    int b    = wg >> 6;
    int slab = wg & 63;
    int t0   = slab * 128;
    int wv = tid >> 6, ln = tid & 63, lo = ln & 15, quad = ln >> 4;
    const size_t hb = (size_t)b * T * C;

    float hreg[32];   // h[c = wv*16+quad*4+r][t = t0+ct*16+lo], idx ct*4+r (ct 0..7)
    float ssum[32];

    // ---- pre-net: hreg + Xo; tail-store 1 row (layer-0 d=1) ----
    {
        const float* xr = xc + b * T;
#pragma unroll
        for (int ct = 0; ct < 8; ct++){
            int t = t0 + ct * 16 + lo;
            float x0 = (t >= 2) ? xr[t - 2] : 0.f;
            float x1 = (t >= 1) ? xr[t - 1] : 0.f;
            float x2 = xr[t];
            bf16x4 hv;
#pragma unroll
            for (int r = 0; r < 4; r++){
                int c = wv * 16 + quad * 4 + r;
                float acc = misc[384 + c] + misc[c*3]*x0 + misc[c*3+1]*x1 + misc[c*3+2]*x2;
                hreg[ct * 4 + r] = acc;
                hv[r] = f2bf(acc);
            }
            *(bf16x4*)(Xo + (ct * 16 + lo) * XS + wv * 16 + quad * 4) = hv;
        }
    }
#pragma unroll
    for (int i = 0; i < 32; i++) ssum[i] = 0.f;
    __syncthreads();
    if (slab < 63) tail_store(Xo, hA + hb + (size_t)t0 * C, 1, tid);
    __syncthreads();
    if (tid == 0)
        __hip_atomic_store(prog + wg, 1u, __ATOMIC_RELAXED, __HIP_MEMORY_SCOPE_AGENT);

    // ---- 40 residual blocks ----
    for (int i = 0; i < NBLK; i++){
        int d  = 1 << (i % 10);
        int D  = (d >= 128) ? (d >> 7) : 1;
        int dn = (i < NBLK - 1) ? (1 << ((i + 1) % 10)) : 0;
        int Dn = (dn >= 128) ? (dn >> 7) : 1;
        int nst = (dn < 128) ? dn : 128;
        bool last = (i == NBLK - 1);
        bool do_store = !last && (slab + Dn <= 63);
        const bf16* hin  = (i & 1) ? hB : hA;
        bf16*       hout = (i & 1) ? hA : hB;
        const bf16* wb   = weff + ((size_t)i << 16);
        const bf16* pwb  = pwc  + i * 16384;
        const float* cb  = cbf + i * 256;
        const float* pb  = pbf + i * 128;

        f32x4 cacc0[8] = {}, cacc1[8] = {};

        // ---- phase A: tap-t MFMA from Xo (weights loaded once) ----
#pragma unroll
        for (int kk = 0; kk < 4; kk++){
            int ko = 128 + kk * 32 + quad * 8;
            bf16x8 a0 = *(const bf16x8*)(wb + (size_t)(wv*16 + lo) * 256 + ko);
            bf16x8 a1 = *(const bf16x8*)(wb + (size_t)(128 + wv*16 + lo) * 256 + ko);
#pragma unroll
            for (int ct = 0; ct < 8; ct++){
                bf16x8 bf_ = *(const bf16x8*)(Xo + (ct*16 + lo) * XS + kk*32 + quad*8);
                cacc0[ct] = MFMA(a0, bf_, cacc0[ct]);
                cacc1[ct] = MFMA(a1, bf_, cacc1[ct]);
            }
        }
        // producer handshake: ALL threads poll
        if (slab >= D) wait_ge(prog + (wg - D), (unsigned)(i + 1));
        // ---- phase B: stage tap rows [t0-d, t0+128-d) into Xh ----
        {
            int tbase = t0 - d;
#pragma unroll
            for (int j = 0; j < 8; j++){
                int g = j * 512 + tid;          // 4096 granules of 8B
                int row = g >> 5, c4 = (g & 31) << 2;
                int t = tbase + row;
                bf16x4 v = {};
                if (t >= t0)      v = *(const bf16x4*)(Xo + (t - t0) * XS + c4);
                else if (t >= 0)  v = ld8(hin + hb + (size_t)t * C + c4);
                *(bf16x4*)(Xh + row * XS + c4) = v;
            }
        }
        __syncthreads();                                   // S1: staging complete
        if (!last && tid == 0)
            __hip_atomic_store(cons + wg, (unsigned)(i + 1),
                               __ATOMIC_RELAXED, __HIP_MEMORY_SCOPE_AGENT);
        // ---- phase C: tap t-d MFMA from Xh ----
#pragma unroll
        for (int kk = 0; kk < 4; kk++){
            int ko = kk * 32 + quad * 8;
            bf16x8 a0 = *(const bf16x8*)(wb + (size_t)(wv*16 + lo) * 256 + ko);
            bf16x8 a1 = *(const bf16x8*)(wb + (size_t)(128 + wv*16 + lo) * 256 + ko);
#pragma unroll
            for (int ct = 0; ct < 8; ct++){
                bf16x8 bf_ = *(const bf16x8*)(Xh + (ct*16 + lo) * XS + kk*32 + quad*8);
                cacc0[ct] = MFMA(a0, bf_, cacc0[ct]);
                cacc1[ct] = MFMA(a1, bf_, cacc1[ct]);
            }
        }
        // ---- phase D: GLU -> S into Xs (no barrier needed after C) ----
#pragma unroll
        for (int ct = 0; ct < 8; ct++){
            int col = ct * 16 + lo;
            bf16x4 sv;
#pragma unroll
            for (int r = 0; r < 4; r++){
                int j = wv * 16 + quad * 4 + r;
                float a = cacc0[ct][r] + cb[j];
                float g = cacc1[ct][r] + cb[128 + j];
                float s = a * __builtin_amdgcn_rcpf(1.f + __expf(-g));
                ssum[ct * 4 + r] += s;
                sv[r] = f2bf(s);
            }
            if (!last) *(bf16x4*)(Xs + col * XS + wv * 16 + quad * 4) = sv;
        }
        if (last) break;                                   // ssum complete
        __syncthreads();                                   // S2: Xs visible
        // ---- phase E: post MFMA + residual -> Xo; register tail-store ----
        {
            f32x4 pacc[8] = {};
#pragma unroll
            for (int kk = 0; kk < 4; kk++){
                bf16x8 pa = *(const bf16x8*)(pwb + (wv*16 + lo) * 128 + kk*32 + quad*8);
#pragma unroll
                for (int ct = 0; ct < 8; ct++){
                    bf16x8 pbv = *(const bf16x8*)(Xs + (ct*16 + lo) * XS + kk*32 + quad*8);
                    pacc[ct] = MFMA(pa, pbv, pacc[ct]);
                }
            }
            bf16x4 hvv[8];
#pragma unroll
            for (int ct = 0; ct < 8; ct++){
#pragma unroll
                for (int r = 0; r < 4; r++){
                    hreg[ct * 4 + r] += pacc[ct][r] + pb[wv * 16 + quad * 4 + r];
                    hvv[ct][r] = f2bf(hreg[ct * 4 + r]);
                }
                *(bf16x4*)(Xo + (ct * 16 + lo) * XS + wv * 16 + quad * 4) = hvv[ct];
            }
            // anti-overwrite: readers of h^{(i-1)} must be done (ALL threads poll)
            if (do_store && i >= 1){
                int dp = 1 << ((i - 1) % 10);
                int Dp = (dp >= 128) ? (dp >> 7) : 1;
                if (slab + Dp <= 63) wait_ge(cons + (wg + Dp), (unsigned)i);
            }
            if (do_store){
                bf16* dst = hout + hb;
#pragma unroll
                for (int ct = 0; ct < 8; ct++){
                    int col = ct * 16 + lo;
                    if (col >= 128 - nst)
                        st8c(dst + (size_t)(t0 + col) * C + wv * 16 + quad * 4, hvv[ct]);
                }
            }
            asm volatile("s_waitcnt vmcnt(0)" ::: "memory");
        }
        __syncthreads();                    // S3: Xo visible + all stores drained
        if (tid == 0)
            __hip_atomic_store(prog + wg, (unsigned)(i + 2),
                               __ATOMIC_RELAXED, __HIP_MEMORY_SCOPE_AGENT);
    }

    // ---- final: relu(ssum) -> lin1 -> relu -> lin2 -> out [T][B][C] ----
    const float* b1 = misc + 512;
    const float* b2 = misc + 640;
    int isbf = *flag;
    __syncthreads();          // seal last layer's Xh tap reads before reuse
#pragma unroll
    for (int ct = 0; ct < 8; ct++){
        int col = ct * 16 + lo;
        bf16x4 zv;
#pragma unroll
        for (int r = 0; r < 4; r++){
            float z = ssum[ct * 4 + r];
            zv[r] = f2bf(z > 0.f ? z : 0.f);
        }
        *(bf16x4*)(Xs + col * XS + wv * 16 + quad * 4) = zv;
    }
    __syncthreads();
    f32x4 a1[8] = {};
#pragma unroll
    for (int kk = 0; kk < 4; kk++){
        bf16x8 pa = *(const bf16x8*)(w1c + (wv*16 + lo) * 128 + kk*32 + quad*8);
#pragma unroll
        for (int ct = 0; ct < 8; ct++){
            bf16x8 pbv = *(const bf16x8*)(Xs + (ct*16 + lo) * XS + kk*32 + quad*8);
            a1[ct] = MFMA(pa, pbv, a1[ct]);
        }
    }
    __syncthreads();
#pragma unroll
    for (int ct = 0; ct < 8; ct++){
        int col = ct * 16 + lo;
        bf16x4 uv;
#pragma unroll
        for (int r = 0; r < 4; r++){
            int row = wv * 16 + quad * 4 + r;
            float u = a1[ct][r] + b1[row];
            uv[r] = f2bf(u > 0.f ? u : 0.f);
        }
        *(bf16x4*)(Xs + col * XS + wv * 16 + quad * 4) = uv;
    }
    __syncthreads();
    f32x4 a2[8] = {};
#pragma unroll
    for (int kk = 0; kk < 4; kk++){
        bf16x8 pa = *(const bf16x8*)(w2c + (wv*16 + lo) * 128 + kk*32 + quad*8);
#pragma unroll
        for (int ct = 0; ct < 8; ct++){
            bf16x8 pbv = *(const bf16x8*)(Xs + (ct*16 + lo) * XS + kk*32 + quad*8);
            a2[ct] = MFMA(pa, pbv, a2[ct]);
        }
    }
#pragma unroll
    for (int ct = 0; ct < 8; ct++){
        int col = t0 + ct * 16 + lo;
#pragma unroll
        for (int r = 0; r < 4; r++){
            int row = wv * 16 + quad * 4 + r;
            float v = a2[ct][r] + b2[row];
            size_t oi = ((size_t)col * NB + b) * C + row;
            if (isbf) ((bf16*)outv)[oi] = f2bf(v);
            else      ((float*)outv)[oi] = v;
        }
    }
}

extern "C" void kernel_launch(void* const* d_in, const int* in_sizes, int n_in,
                              void* d_out, int out_size, void* d_ws, size_t ws_size,
                              hipStream_t stream){
    const void* x      = d_in[0];
    const void* pre_w  = d_in[1];
    const void* pre_b  = d_in[2];
    const void* conv_w = d_in[3];
    const void* conv_b = d_in[4];
    const void* post_w = d_in[5];
    const void* post_b = d_in[6];
    const void* lin1w  = d_in[7];
    const void* lin1b  = d_in[8];
    const void* lin2w  = d_in[9];
    const void* lin2b  = d_in[10];

    char* ws = (char*)d_ws;
    bf16*     hA   = (bf16*)    (ws);                   //  8,388,608 B
    bf16*     hB   = (bf16*)    (ws +  8388608);        //  8,388,608 B
    bf16*     weff = (bf16*)    (ws + 16777216);        //  5,242,880 B
    bf16*     pwc  = (bf16*)    (ws + 22020096);        //  1,310,720 B
    bf16*     w1c  = (bf16*)    (ws + 23330816);        //     32,768 B
    bf16*     w2c  = (bf16*)    (ws + 23363584);        //     32,768 B
    float*    xc   = (float*)   (ws + 23396352);        //    131,072 B
    float*    cbf  = (float*)   (ws + 23527424);        //     40,960 B
    float*    pbf  = (float*)   (ws + 23568384);        //     20,480 B
    float*    misc = (float*)   (ws + 23588864);        //      3,072 B
    int*      flag = (int*)     (ws + 23591936);        //          4 B
    unsigned* prog = (unsigned*)(ws + 23592960);        //      1,024 B
    unsigned* cons = (unsigned*)(ws + 23593984);        //      1,024 B

    hipMemsetAsync(prog, 0, 2048, stream);
    k_detect<<<1, 64, 0, stream>>>((const unsigned short*)x, flag);
    k_prep<<<1640, 256, 0, stream>>>(conv_w, post_w, lin1w, lin2w, x, conv_b,
                                     post_b, pre_w, pre_b, lin1b, lin2b,
                                     weff, pwc, w1c, w2c, xc, cbf, pbf, misc, flag);

    const float* xc_c   = xc;   const float* misc_c = misc;
    const bf16*  weff_c = weff; const float* cbf_c  = cbf;
    const bf16*  pwc_c  = pwc;  const float* pbf_c  = pbf;
    const bf16*  w1c_c  = w1c;  const bf16*  w2c_c  = w2c;
    void* out_v = d_out;        const int* flag_c = flag;
    void* ka[14] = { &xc_c, &misc_c, &weff_c, &cbf_c, &pwc_c, &pbf_c,
                     &w1c_c, &w2c_c, &hA, &hB, &prog, &cons, &out_v, &flag_c };
    hipLaunchCooperativeKernel((void*)k_main, dim3(256), dim3(512), ka, 0, stream);
}

// Round 10
// 538.892 us; speedup vs baseline: 1.1238x; 1.1238x over previous
//
#include <hip/hip_runtime.h>
#include <hip/hip_bf16.h>

typedef __bf16 bf16;
typedef unsigned long long u64;
typedef __bf16 bf16x8 __attribute__((ext_vector_type(8)));
typedef __bf16 bf16x4 __attribute__((ext_vector_type(4)));
typedef float f32x4 __attribute__((ext_vector_type(4)));

#define NB 4
#define T 8192
#define C 128
#define NBLK 40
#define XS 136   // LDS row stride (bf16): 128 ch + 8 pad

#define MFMA(a, b, c) __builtin_amdgcn_mfma_f32_16x16x32_bf16(a, b, c, 0, 0, 0)

__device__ __forceinline__ float bf2f(bf16 x){ return (float)x; }
__device__ __forceinline__ bf16 f2bf(float x){ return (bf16)x; }

__device__ __forceinline__ float ld(const void* p, int i, int isbf){
    return isbf ? bf2f(((const bf16*)p)[i]) : ((const float*)p)[i];
}

// Coherent 8B load (relaxed agent atomic -> bypasses stale L1/L2;
// compiler manages the waitcnt before use).
__device__ __forceinline__ bf16x4 ld8(const bf16* p){
    u64 v = __hip_atomic_load((const u64*)p, __ATOMIC_RELAXED, __HIP_MEMORY_SCOPE_AGENT);
    return __builtin_bit_cast(bf16x4, v);
}
// Coherent 16B store via asm (inputs only -> safe), caller drains vmcnt.
__device__ __forceinline__ void st16c(bf16* p, f32x4 v){
    asm volatile("global_store_dwordx4 %0, %1, off sc0 sc1" :: "v"(p), "v"(v) : "memory");
}

// Detect input dtype from x's raw bits (bf16 -> low u16s have sane exponents).
__global__ __launch_bounds__(64) void k_detect(const unsigned short* __restrict__ u,
                                               int* __restrict__ flag){
    unsigned short v = u[threadIdx.x * 2];
    int e = (v >> 7) & 255;
    bool sane = (e >= 100 && e <= 140) || ((v & 0x7FFF) == 0);
    unsigned long long m = __ballot(sane);
    if (threadIdx.x == 0) *flag = (__popcll(m) >= 48) ? 1 : 0;
}

// Canonicalize inputs (8 elems per thread).
// weff [40][256][256] bf16: weff[blk][o][c]=cw[blk][o][c][0] (t-d), [o][128+c]=cw[..][1] (t)
__global__ __launch_bounds__(256) void k_prep(
    const void* __restrict__ conv_w, const void* __restrict__ post_w,
    const void* __restrict__ lin1_w, const void* __restrict__ lin2_w,
    const void* __restrict__ x,      const void* __restrict__ conv_b,
    const void* __restrict__ post_b, const void* __restrict__ pre_w,
    const void* __restrict__ pre_b,  const void* __restrict__ lin1_b,
    const void* __restrict__ lin2_b,
    bf16* __restrict__ weff, bf16* __restrict__ pwc,
    bf16* __restrict__ w1c,  bf16* __restrict__ w2c,
    float* __restrict__ xc,  float* __restrict__ cbf,
    float* __restrict__ pbf, float* __restrict__ misc,
    const int* __restrict__ flag){
    int f = *flag;
    int g = blockIdx.x * 256 + threadIdx.x;
    if (g < 327680){                 // weff: 40*256*256/8 granules
        int blk = g >> 13, r = g & 8191, o = r >> 5, j = r & 31;
        int k = (j >= 16) ? 1 : 0;
        int base = blk * 65536 + o * 256 + (j * 8 - k * 128) * 2 + k;
        bf16x8 v;
#pragma unroll
        for (int m = 0; m < 8; m++) v[m] = f2bf(ld(conv_w, base + m * 2, f));
        *(bf16x8*)(weff + (size_t)g * 8) = v;
    } else if (g < 409600){          // pwc
        int e = (g - 327680) * 8;
        bf16x8 v;
#pragma unroll
        for (int m = 0; m < 8; m++) v[m] = f2bf(ld(post_w, e + m, f));
        *(bf16x8*)(pwc + e) = v;
    } else if (g < 411648){          // w1c
        int e = (g - 409600) * 8;
        bf16x8 v;
#pragma unroll
        for (int m = 0; m < 8; m++) v[m] = f2bf(ld(lin1_w, e + m, f));
        *(bf16x8*)(w1c + e) = v;
    } else if (g < 413696){          // w2c
        int e = (g - 411648) * 8;
        bf16x8 v;
#pragma unroll
        for (int m = 0; m < 8; m++) v[m] = f2bf(ld(lin2_w, e + m, f));
        *(bf16x8*)(w2c + e) = v;
    } else if (g < 417792){          // xc (f32)
        int e = (g - 413696) * 8;
#pragma unroll
        for (int m = 0; m < 8; m++) xc[e + m] = ld(x, e + m, f);
    } else if (g < 419072){          // cbf
        int e = (g - 417792) * 8;
#pragma unroll
        for (int m = 0; m < 8; m++) cbf[e + m] = ld(conv_b, e + m, f);
    } else if (g < 419712){          // pbf
        int e = (g - 419072) * 8;
#pragma unroll
        for (int m = 0; m < 8; m++) pbf[e + m] = ld(post_b, e + m, f);
    } else if (g < 419808){          // misc
        int e = (g - 419712) * 8;
#pragma unroll
        for (int m = 0; m < 8; m++){
            int idx = e + m;
            if      (idx < 384) misc[idx] = ld(pre_w,  idx,       f);
            else if (idx < 512) misc[idx] = ld(pre_b,  idx - 384, f);
            else if (idx < 640) misc[idx] = ld(lin1_b, idx - 512, f);
            else                misc[idx] = ld(lin2_b, idx - 640, f);
        }
    }
}

__device__ __forceinline__ void wait_ge(unsigned* p, unsigned v){
    int guard = 0;
    while (__hip_atomic_load(p, __ATOMIC_RELAXED, __HIP_MEMORY_SCOPE_AGENT) < v){
        __builtin_amdgcn_s_sleep(1);
        if (++guard > (1 << 22)) break;   // failsafe against protocol bugs
    }
    asm volatile("" ::: "memory");
}

// Store tail rows [128-nrows, 128) of Xo to dst (global, coherent), then drain.
// One row = 128 bf16 = 256 B = SIXTEEN 16B granules -> 16 consecutive threads
// write one full row: coalesced, no HBM sector amplification (round-9 lesson:
// scattered 8B register stores cost +80MB WRITE_SIZE and +58us).
__device__ __forceinline__ void tail_store(const bf16* Xo, bf16* dst, int nrows, int tid){
    int ngr = nrows * 16;                      // 16B granules
    for (int g = tid; g < ngr; g += 512){
        int rr = 128 - nrows + (g >> 4), co = (g & 15) * 8;
        f32x4 v = *(const f32x4*)(Xo + rr * XS + co);
        st16c(dst + (size_t)rr * C + co, v);
    }
    asm volatile("s_waitcnt vmcnt(0)" ::: "memory");
}

// Persistent kernel, 256 WGs x 512 threads, 1 WG/CU (proven geometry).
// FOUR barriers/layer (round-5 had 5; round-9's 3-barrier variant regressed
// on store amplification — this keeps round-5 memory behavior + Xs buffer):
//   A: tap-t MFMA from Xo (no deps)  ||  poll prog (all threads)
//   B: stage Xh rows [t0-d, t0+128-d)  (LDS 16B copy for rows>=d, global 8B below)
//                                                 S1  (tid0 publishes cons)
//   C: tap-d MFMA from Xh
//   D: GLU -> S into Xs  (third buffer: no WAR vs C's Xh reads -> no barrier C->D)
//                                                 S2  (Xs visible)
//   E: post MFMA from Xs + residual -> Xo; anti-overwrite poll
//                                                 S3  (Xo visible)
//   F: tail_store 16B coalesced from Xo + drain
//                                                 S4  (stores drained)
//      tid0 publishes prog
// Handshake semantics byte-identical to the 456us round-5 kernel.
// prog[w] = stages published (pre=1, layer i => i+2); cons[w] = staging reads done.
__global__ __launch_bounds__(512, 2) void k_main(
    const float* __restrict__ xc,  const float* __restrict__ misc,
    const bf16* __restrict__ weff, const float* __restrict__ cbf,
    const bf16* __restrict__ pwc,  const float* __restrict__ pbf,
    const bf16* __restrict__ w1c,  const bf16* __restrict__ w2c,
    bf16* __restrict__ hA, bf16* __restrict__ hB,
    unsigned* __restrict__ prog, unsigned* __restrict__ cons,
    void* __restrict__ outv, const int* __restrict__ flag)
{
    __shared__ __align__(16) bf16 Xo[128 * XS];  // own h^{(i)} tile (34,816 B)
    __shared__ __align__(16) bf16 Xh[128 * XS];  // staged tap tile (34,816 B)
    __shared__ __align__(16) bf16 Xs[128 * XS];  // skip S / Z / U  (34,816 B)

    int tid  = threadIdx.x;
    int wg   = blockIdx.x;             // 256
    int b    = wg >> 6;
    int slab = wg & 63;
    int t0   = slab * 128;
    int wv = tid >> 6, ln = tid & 63, lo = ln & 15, quad = ln >> 4;
    const size_t hb = (size_t)b * T * C;

    float hreg[32];   // h[c = wv*16+quad*4+r][t = t0+ct*16+lo], idx ct*4+r (ct 0..7)
    float ssum[32];

    // ---- pre-net: hreg + Xo; tail-store 1 row (layer-0 d=1) ----
    {
        const float* xr = xc + b * T;
#pragma unroll
        for (int ct = 0; ct < 8; ct++){
            int t = t0 + ct * 16 + lo;
            float x0 = (t >= 2) ? xr[t - 2] : 0.f;
            float x1 = (t >= 1) ? xr[t - 1] : 0.f;
            float x2 = xr[t];
            bf16x4 hv;
#pragma unroll
            for (int r = 0; r < 4; r++){
                int c = wv * 16 + quad * 4 + r;
                float acc = misc[384 + c] + misc[c*3]*x0 + misc[c*3+1]*x1 + misc[c*3+2]*x2;
                hreg[ct * 4 + r] = acc;
                hv[r] = f2bf(acc);
            }
            *(bf16x4*)(Xo + (ct * 16 + lo) * XS + wv * 16 + quad * 4) = hv;
        }
    }
#pragma unroll
    for (int i = 0; i < 32; i++) ssum[i] = 0.f;
    __syncthreads();
    if (slab < 63) tail_store(Xo, hA + hb + (size_t)t0 * C, 1, tid);
    __syncthreads();
    if (tid == 0)
        __hip_atomic_store(prog + wg, 1u, __ATOMIC_RELAXED, __HIP_MEMORY_SCOPE_AGENT);

    // ---- 40 residual blocks ----
    for (int i = 0; i < NBLK; i++){
        int d  = 1 << (i % 10);
        int D  = (d >= 128) ? (d >> 7) : 1;
        int dn = (i < NBLK - 1) ? (1 << ((i + 1) % 10)) : 0;
        int Dn = (dn >= 128) ? (dn >> 7) : 1;
        int nst = (dn < 128) ? dn : 128;
        bool last = (i == NBLK - 1);
        bool do_store = !last && (slab + Dn <= 63);
        const bf16* hin  = (i & 1) ? hB : hA;
        bf16*       hout = (i & 1) ? hA : hB;
        const bf16* wb   = weff + ((size_t)i << 16);
        const bf16* pwb  = pwc  + i * 16384;
        const float* cb  = cbf + i * 256;
        const float* pb  = pbf + i * 128;

        f32x4 cacc0[8] = {}, cacc1[8] = {};

        // ---- phase A: tap-t MFMA from Xo (weights loaded once) ----
#pragma unroll
        for (int kk = 0; kk < 4; kk++){
            int ko = 128 + kk * 32 + quad * 8;
            bf16x8 a0 = *(const bf16x8*)(wb + (size_t)(wv*16 + lo) * 256 + ko);
            bf16x8 a1 = *(const bf16x8*)(wb + (size_t)(128 + wv*16 + lo) * 256 + ko);
#pragma unroll
            for (int ct = 0; ct < 8; ct++){
                bf16x8 bf_ = *(const bf16x8*)(Xo + (ct*16 + lo) * XS + kk*32 + quad*8);
                cacc0[ct] = MFMA(a0, bf_, cacc0[ct]);
                cacc1[ct] = MFMA(a1, bf_, cacc1[ct]);
            }
        }
        // producer handshake: ALL threads poll
        if (slab >= D) wait_ge(prog + (wg - D), (unsigned)(i + 1));
        // ---- phase B: stage tap rows [t0-d, t0+128-d) into Xh ----
        {
            int bcut = (d < 128) ? d : 128;       // rows below bcut come from global
            // LDS->LDS copy (16B granules): rows [bcut, 128) <- Xo rows [0, 128-d)
            int ngr16 = (128 - bcut) * 16;
            for (int g = tid; g < ngr16; g += 512){
                int row = bcut + (g >> 4), co = (g & 15) * 8;
                f32x4 v = *(const f32x4*)(Xo + (row - d) * XS + co);
                *(f32x4*)(Xh + row * XS + co) = v;
            }
            // global coherent (8B granules): rows [0, bcut)
            int tbase = t0 - d;
            int ngr8 = bcut * 32;
            for (int g = tid; g < ngr8; g += 512){
                int row = g >> 5, c4 = (g & 31) << 2;
                int t = tbase + row;
                bf16x4 v = {};
                if (t >= 0) v = ld8(hin + hb + (size_t)t * C + c4);
                *(bf16x4*)(Xh + row * XS + c4) = v;
            }
        }
        __syncthreads();                                   // S1: staging complete
        if (!last && tid == 0)
            __hip_atomic_store(cons + wg, (unsigned)(i + 1),
                               __ATOMIC_RELAXED, __HIP_MEMORY_SCOPE_AGENT);
        // ---- phase C: tap t-d MFMA from Xh ----
#pragma unroll
        for (int kk = 0; kk < 4; kk++){
            int ko = kk * 32 + quad * 8;
            bf16x8 a0 = *(const bf16x8*)(wb + (size_t)(wv*16 + lo) * 256 + ko);
            bf16x8 a1 = *(const bf16x8*)(wb + (size_t)(128 + wv*16 + lo) * 256 + ko);
#pragma unroll
            for (int ct = 0; ct < 8; ct++){
                bf16x8 bf_ = *(const bf16x8*)(Xh + (ct*16 + lo) * XS + kk*32 + quad*8);
                cacc0[ct] = MFMA(a0, bf_, cacc0[ct]);
                cacc1[ct] = MFMA(a1, bf_, cacc1[ct]);
            }
        }
        // ---- phase D: GLU -> S into Xs (no barrier needed after C) ----
#pragma unroll
        for (int ct = 0; ct < 8; ct++){
            int col = ct * 16 + lo;
            bf16x4 sv;
#pragma unroll
            for (int r = 0; r < 4; r++){
                int j = wv * 16 + quad * 4 + r;
                float a = cacc0[ct][r] + cb[j];
                float g = cacc1[ct][r] + cb[128 + j];
                float s = a * __builtin_amdgcn_rcpf(1.f + __expf(-g));
                ssum[ct * 4 + r] += s;
                sv[r] = f2bf(s);
            }
            if (!last) *(bf16x4*)(Xs + col * XS + wv * 16 + quad * 4) = sv;
        }
        if (last) break;                                   // ssum complete
        __syncthreads();                                   // S2: Xs visible
        // ---- phase E: post MFMA + residual -> Xo ----
        {
            f32x4 pacc[8] = {};
#pragma unroll
            for (int kk = 0; kk < 4; kk++){
                bf16x8 pa = *(const bf16x8*)(pwb + (wv*16 + lo) * 128 + kk*32 + quad*8);
#pragma unroll
                for (int ct = 0; ct < 8; ct++){
                    bf16x8 pbv = *(const bf16x8*)(Xs + (ct*16 + lo) * XS + kk*32 + quad*8);
                    pacc[ct] = MFMA(pa, pbv, pacc[ct]);
                }
            }
#pragma unroll
            for (int ct = 0; ct < 8; ct++){
                bf16x4 hv;
#pragma unroll
                for (int r = 0; r < 4; r++){
                    hreg[ct * 4 + r] += pacc[ct][r] + pb[wv * 16 + quad * 4 + r];
                    hv[r] = f2bf(hreg[ct * 4 + r]);
                }
                *(bf16x4*)(Xo + (ct * 16 + lo) * XS + wv * 16 + quad * 4) = hv;
            }
        }
        // anti-overwrite: readers of h^{(i-1)} must be done (ALL threads poll)
        if (do_store && i >= 1){
            int dp = 1 << ((i - 1) % 10);
            int Dp = (dp >= 128) ? (dp >> 7) : 1;
            if (slab + Dp <= 63) wait_ge(cons + (wg + Dp), (unsigned)i);
        }
        __syncthreads();                                   // S3: Xo h^{(i+1)} visible
        // ---- phase F: coalesced tail store ----
        if (do_store) tail_store(Xo, hout + hb + (size_t)t0 * C, nst, tid);
        __syncthreads();                                   // S4: all stores drained
        if (tid == 0)
            __hip_atomic_store(prog + wg, (unsigned)(i + 2),
                               __ATOMIC_RELAXED, __HIP_MEMORY_SCOPE_AGENT);
    }

    // ---- final: relu(ssum) -> lin1 -> relu -> lin2 -> out [T][B][C] ----
    const float* b1 = misc + 512;
    const float* b2 = misc + 640;
    int isbf = *flag;
    __syncthreads();          // seal last layer's LDS reads before reuse
#pragma unroll
    for (int ct = 0; ct < 8; ct++){
        int col = ct * 16 + lo;
        bf16x4 zv;
#pragma unroll
        for (int r = 0; r < 4; r++){
            float z = ssum[ct * 4 + r];
            zv[r] = f2bf(z > 0.f ? z : 0.f);
        }
        *(bf16x4*)(Xs + col * XS + wv * 16 + quad * 4) = zv;
    }
    __syncthreads();
    f32x4 a1[8] = {};
#pragma unroll
    for (int kk = 0; kk < 4; kk++){
        bf16x8 pa = *(const bf16x8*)(w1c + (wv*16 + lo) * 128 + kk*32 + quad*8);
#pragma unroll
        for (int ct = 0; ct < 8; ct++){
            bf16x8 pbv = *(const bf16x8*)(Xs + (ct*16 + lo) * XS + kk*32 + quad*8);
            a1[ct] = MFMA(pa, pbv, a1[ct]);
        }
    }
    __syncthreads();
#pragma unroll
    for (int ct = 0; ct < 8; ct++){
        int col = ct * 16 + lo;
        bf16x4 uv;
#pragma unroll
        for (int r = 0; r < 4; r++){
            int row = wv * 16 + quad * 4 + r;
            float u = a1[ct][r] + b1[row];
            uv[r] = f2bf(u > 0.f ? u : 0.f);
        }
        *(bf16x4*)(Xs + col * XS + wv * 16 + quad * 4) = uv;
    }
    __syncthreads();
    f32x4 a2[8] = {};
#pragma unroll
    for (int kk = 0; kk < 4; kk++){
        bf16x8 pa = *(const bf16x8*)(w2c + (wv*16 + lo) * 128 + kk*32 + quad*8);
#pragma unroll
        for (int ct = 0; ct < 8; ct++){
            bf16x8 pbv = *(const bf16x8*)(Xs + (ct*16 + lo) * XS + kk*32 + quad*8);
            a2[ct] = MFMA(pa, pbv, a2[ct]);
        }
    }
#pragma unroll
    for (int ct = 0; ct < 8; ct++){
        int col = t0 + ct * 16 + lo;
#pragma unroll
        for (int r = 0; r < 4; r++){
            int row = wv * 16 + quad * 4 + r;
            float v = a2[ct][r] + b2[row];
            size_t oi = ((size_t)col * NB + b) * C + row;
            if (isbf) ((bf16*)outv)[oi] = f2bf(v);
            else      ((float*)outv)[oi] = v;
        }
    }
}

extern "C" void kernel_launch(void* const* d_in, const int* in_sizes, int n_in,
                              void* d_out, int out_size, void* d_ws, size_t ws_size,
                              hipStream_t stream){
    const void* x      = d_in[0];
    const void* pre_w  = d_in[1];
    const void* pre_b  = d_in[2];
    const void* conv_w = d_in[3];
    const void* conv_b = d_in[4];
    const void* post_w = d_in[5];
    const void* post_b = d_in[6];
    const void* lin1w  = d_in[7];
    const void* lin1b  = d_in[8];
    const void* lin2w  = d_in[9];
    const void* lin2b  = d_in[10];

    char* ws = (char*)d_ws;
    bf16*     hA   = (bf16*)    (ws);                   //  8,388,608 B
    bf16*     hB   = (bf16*)    (ws +  8388608);        //  8,388,608 B
    bf16*     weff = (bf16*)    (ws + 16777216);        //  5,242,880 B
    bf16*     pwc  = (bf16*)    (ws + 22020096);        //  1,310,720 B
    bf16*     w1c  = (bf16*)    (ws + 23330816);        //     32,768 B
    bf16*     w2c  = (bf16*)    (ws + 23363584);        //     32,768 B
    float*    xc   = (float*)   (ws + 23396352);        //    131,072 B
    float*    cbf  = (float*)   (ws + 23527424);        //     40,960 B
    float*    pbf  = (float*)   (ws + 23568384);        //     20,480 B
    float*    misc = (float*)   (ws + 23588864);        //      3,072 B
    int*      flag = (int*)     (ws + 23591936);        //          4 B
    unsigned* prog = (unsigned*)(ws + 23592960);        //      1,024 B
    unsigned* cons = (unsigned*)(ws + 23593984);        //      1,024 B

    hipMemsetAsync(prog, 0, 2048, stream);
    k_detect<<<1, 64, 0, stream>>>((const unsigned short*)x, flag);
    k_prep<<<1640, 256, 0, stream>>>(conv_w, post_w, lin1w, lin2w, x, conv_b,
                                     post_b, pre_w, pre_b, lin1b, lin2b,
                                     weff, pwc, w1c, w2c, xc, cbf, pbf, misc, flag);

    const float* xc_c   = xc;   const float* misc_c = misc;
    const bf16*  weff_c = weff; const float* cbf_c  = cbf;
    const bf16*  pwc_c  = pwc;  const float* pbf_c  = pbf;
    const bf16*  w1c_c  = w1c;  const bf16*  w2c_c  = w2c;
    void* out_v = d_out;        const int* flag_c = flag;
    void* ka[14] = { &xc_c, &misc_c, &weff_c, &cbf_c, &pwc_c, &pbf_c,
                     &w1c_c, &w2c_c, &hA, &hB, &prog, &cons, &out_v, &flag_c };
    hipLaunchCooperativeKernel((void*)k_main, dim3(256), dim3(512), ka, 0, stream);
}